// Round 1
// 228.921 us; speedup vs baseline: 1.0736x; 1.0736x over previous
//
#include <hip/hip_runtime.h>
#include <hip/hip_bf16.h>

#define BB 32
#define SS 1024
#define HHH 768
#define EE 128
#define WW 8
#define PP 512
#define RDD 32

typedef __attribute__((ext_vector_type(8))) short bf16x8;
typedef __attribute__((ext_vector_type(8))) unsigned short us8;
typedef __attribute__((ext_vector_type(4))) unsigned short us4;
typedef __attribute__((ext_vector_type(4))) float f32x4;

__device__ __forceinline__ unsigned short f2bf(float v) {
    __hip_bfloat16 h = __float2bfloat16(v);
    return *(unsigned short*)&h;
}

// ---------------------------------------------------------------------------
// K1: merged pool + prep (unchanged).
// ---------------------------------------------------------------------------
__global__ __launch_bounds__(256) void pool_prep_kernel(
    const float* __restrict__ seq, const int* __restrict__ starts,
    const int* __restrict__ types, const float* __restrict__ temb,
    unsigned short* __restrict__ xout,
    const float* __restrict__ W1, unsigned short* __restrict__ Wt,
    const float* __restrict__ Wr1, unsigned short* __restrict__ Wtr,
    const float* __restrict__ W2, unsigned short* __restrict__ W2t,
    const float* __restrict__ remb, unsigned short* __restrict__ rembb,
    float* __restrict__ basep) {
    int tid = threadIdx.x;
    __shared__ float sbuf[WW * HHH];
    __shared__ float scred[WW];
    __shared__ float attn_s[WW];

    if (blockIdx.x < BB * EE) {
        int be = blockIdx.x;
        int b = be >> 7;
        int start = starts[be];
        const float4* bp4 = (const float4*)(seq + ((size_t)b * SS + start) * HHH);
        for (int idx = tid; idx < WW * (HHH / 4); idx += 256) {
            int w = idx / (HHH / 4), h4 = idx % (HHH / 4);
            float4 v = bp4[(size_t)w * (HHH / 4) + h4];
            sbuf[w * HHH + h4 * 4 + 0] = v.x; sbuf[w * HHH + h4 * 4 + 1] = v.y;
            sbuf[w * HHH + h4 * 4 + 2] = v.z; sbuf[w * HHH + h4 * 4 + 3] = v.w;
        }
        __syncthreads();

        float sc[WW];
#pragma unroll
        for (int w = 0; w < WW; w++) sc[w] = 0.f;
#pragma unroll
        for (int c = 0; c < 3; c++) {
            int h = tid + 256 * c;
            float s = 0.f;
#pragma unroll
            for (int w = 0; w < WW; w++) s += sbuf[w * HHH + h];
            float m = s * (1.0f / WW);
#pragma unroll
            for (int w = 0; w < WW; w++) sc[w] += sbuf[w * HHH + h] * m;
        }
        if (tid < WW) scred[tid] = 0.f;
        __syncthreads();
        int lane = tid & 63;
#pragma unroll
        for (int w = 0; w < WW; w++) {
            float v = sc[w];
            for (int o = 32; o > 0; o >>= 1) v += __shfl_down(v, o, 64);
            if (lane == 0) atomicAdd(&scred[w], v);
        }
        __syncthreads();
        if (tid == 0) {
            float mx = scred[0];
            for (int w = 1; w < WW; w++) mx = fmaxf(mx, scred[w]);
            float ssum = 0.f;
            float a[WW];
            for (int w = 0; w < WW; w++) { a[w] = __expf(scred[w] - mx); ssum += a[w]; }
            float inv = 1.f / ssum;
            for (int w = 0; w < WW; w++) attn_s[w] = a[w] * inv;
        }
        __syncthreads();

        int t = types[be];
        const float* emb = temb + (size_t)t * HHH;
#pragma unroll
        for (int c = 0; c < 3; c++) {
            int h = tid + 256 * c;
            float p = 0.f;
#pragma unroll
            for (int w = 0; w < WW; w++) p += attn_s[w] * sbuf[w * HHH + h];
            xout[(size_t)be * HHH + h] = f2bf(p + emb[h]);
        }
        return;
    }

    int blk = blockIdx.x - BB * EE;
    if (blk < 48) {
        int k0 = blk * 16;
        for (int i = tid; i < 16 * 256; i += 256)
            sbuf[i] = W1[(size_t)(k0 + (i >> 8)) * 256 + (i & 255)];
        __syncthreads();
        int n = tid;
        us8 v0, v1;
#pragma unroll
        for (int kk = 0; kk < 8; kk++) v0[kk] = f2bf(sbuf[kk * 256 + n]);
#pragma unroll
        for (int kk = 0; kk < 8; kk++) v1[kk] = f2bf(sbuf[(8 + kk) * 256 + n]);
        *(us8*)(Wt + (size_t)n * HHH + k0) = v0;
        *(us8*)(Wt + (size_t)n * HHH + k0 + 8) = v1;
    } else if (blk < 58) {
        int k0 = (blk - 48) * 16;
        for (int i = tid; i < 16 * 256; i += 256)
            sbuf[i] = Wr1[(size_t)(k0 + (i >> 8)) * 256 + (i & 255)];
        __syncthreads();
        int n = tid;
        us8 v0, v1;
#pragma unroll
        for (int kk = 0; kk < 8; kk++) v0[kk] = f2bf(sbuf[kk * 256 + n]);
#pragma unroll
        for (int kk = 0; kk < 8; kk++) v1[kk] = f2bf(sbuf[(8 + kk) * 256 + n]);
        *(us8*)(Wtr + (size_t)n * 160 + k0) = v0;
        *(us8*)(Wtr + (size_t)n * 160 + k0 + 8) = v1;
    } else if (blk < 74) {
        int k0 = (blk - 58) * 16;
        for (int i = tid; i < 16 * 64; i += 256)
            sbuf[(i >> 6) * 64 + (i & 63)] = W2[(size_t)(k0 + (i >> 6)) * 64 + (i & 63)];
        __syncthreads();
        if (tid < 64) {
            int n = tid;
            us8 v0, v1;
#pragma unroll
            for (int kk = 0; kk < 8; kk++) v0[kk] = f2bf(sbuf[kk * 64 + n]);
#pragma unroll
            for (int kk = 0; kk < 8; kk++) v1[kk] = f2bf(sbuf[(8 + kk) * 64 + n]);
            *(us8*)(W2t + (size_t)n * 256 + k0) = v0;
            *(us8*)(W2t + (size_t)n * 256 + k0 + 8) = v1;
        }
    } else if (blk == 74) {
        for (int i = tid; i < 9 * RDD; i += 256) rembb[i] = f2bf(remb[i]);
    } else {
        int pc = blk - 75;
        int kc = pc % 12;
        int b = pc / 12;
        int n = tid;
        if (n < 64) sbuf[4096 + n] = seq[(size_t)b * SS * HHH + kc * 64 + n];
        __syncthreads();
        float acc = 0.f;
        const float* w = Wr1 + (size_t)(160 + kc * 64) * 256 + n;
#pragma unroll 16
        for (int k = 0; k < 64; k++) acc += sbuf[4096 + k] * w[(size_t)k * 256];
        basep[((size_t)kc * 32 + b) * 256 + n] = acc;
    }
}

// ---------------------------------------------------------------------------
// K2: GEMM1 via MFMA bf16, fused sd1 partial dots + bf16 transposed output.
// Xb(4096x768) @ Wt^T -> h1Tg[b][h][d][j] bf16, ps_s/ps_d[nb][row*2+h].
// ---------------------------------------------------------------------------
__global__ __launch_bounds__(256) void gemm1_mfma_kernel(
    const unsigned short* __restrict__ Xb, const unsigned short* __restrict__ Wt,
    const float* __restrict__ asrc1, const float* __restrict__ adst1,
    unsigned short* __restrict__ h1Tg,
    float* __restrict__ ps_s, float* __restrict__ ps_d) {
    const int K = HHH;
    int n0 = blockIdx.x * 64;
    int m0 = blockIdx.y * 64;
    int tid = threadIdx.x;
    int wave = tid >> 6, lane = tid & 63;
    int wm = (wave >> 1) * 32, wn = (wave & 1) * 32;

    __shared__ __align__(16) unsigned short As[64][40];
    __shared__ __align__(16) unsigned short Bs[64][40];
    __shared__ __align__(16) unsigned short T[64][72];   // [n_local][m_local]
    __shared__ float sdred[64][2][2];

    f32x4 acc[2][2] = {};
    int ar = tid >> 2;
    int ac = (tid & 3) * 8;
    int fr = lane & 15;
    int fk = (lane >> 4) * 8;

    for (int k0 = 0; k0 < K; k0 += 32) {
        us8 av = *(const us8*)(Xb + (size_t)(m0 + ar) * K + k0 + ac);
        us8 bv = *(const us8*)(Wt + (size_t)(n0 + ar) * K + k0 + ac);
        *(us8*)(&As[ar][ac]) = av;
        *(us8*)(&Bs[ar][ac]) = bv;
        __syncthreads();

        bf16x8 a0 = *(const bf16x8*)(&As[wm + fr][fk]);
        bf16x8 a1 = *(const bf16x8*)(&As[wm + 16 + fr][fk]);
        bf16x8 b0 = *(const bf16x8*)(&Bs[wn + fr][fk]);
        bf16x8 b1 = *(const bf16x8*)(&Bs[wn + 16 + fr][fk]);

        acc[0][0] = __builtin_amdgcn_mfma_f32_16x16x32_bf16(a0, b0, acc[0][0], 0, 0, 0);
        acc[0][1] = __builtin_amdgcn_mfma_f32_16x16x32_bf16(a0, b1, acc[0][1], 0, 0, 0);
        acc[1][0] = __builtin_amdgcn_mfma_f32_16x16x32_bf16(a1, b0, acc[1][0], 0, 0, 0);
        acc[1][1] = __builtin_amdgcn_mfma_f32_16x16x32_bf16(a1, b1, acc[1][1], 0, 0, 0);
        __syncthreads();
    }

    int crow = (lane >> 4) * 4;
    int ccol = lane & 15;
    int h = n0 >> 7;               // head of this n-block
    int nb = (n0 >> 6) & 1;        // which half of the head's 128 d's
    int dbase = (n0 & 127) + wn;

    float asv[2], adv[2];
#pragma unroll
    for (int ni = 0; ni < 2; ni++) {
        int d = dbase + ni * 16 + ccol;
        asv[ni] = asrc1[h * 128 + d];
        adv[ni] = adst1[h * 128 + d];
    }

#pragma unroll
    for (int mi = 0; mi < 2; mi++) {
#pragma unroll
        for (int r = 0; r < 4; r++) {
            float sp = 0.f, dp = 0.f;
#pragma unroll
            for (int ni = 0; ni < 2; ni++) {
                float v = acc[mi][ni][r];
                T[wn + ni * 16 + ccol][wm + mi * 16 + crow + r] = f2bf(v);
                sp += v * asv[ni];
                dp += v * adv[ni];
            }
            for (int msk = 1; msk < 16; msk <<= 1) {
                sp += __shfl_xor(sp, msk, 64);
                dp += __shfl_xor(dp, msk, 64);
            }
            if ((lane & 15) == 0) {
                int row = wm + mi * 16 + crow + r;
                sdred[row][wn >> 5][0] = sp;
                sdred[row][wn >> 5][1] = dp;
            }
        }
    }
    __syncthreads();

    int b = m0 >> 7;
    int j0 = m0 & 127;
    if (tid < 64) {
        float spt = sdred[tid][0][0] + sdred[tid][1][0];
        float dpt = sdred[tid][0][1] + sdred[tid][1][1];
        size_t o = (size_t)nb * 8192 + ((size_t)(m0 + tid)) * 2 + h;
        ps_s[o] = spt;
        ps_d[o] = dpt;
    }
    {
        int d_l = tid >> 2, q = tid & 3;
        us8 v0 = *(const us8*)(&T[d_l][q * 16]);
        us8 v1 = *(const us8*)(&T[d_l][q * 16 + 8]);
        size_t go = ((size_t)(b * 2 + h) * 128 + (n0 & 127) + d_l) * 128 + j0 + q * 16;
        *(us8*)(h1Tg + go) = v0;
        *(us8*)(h1Tg + go + 8) = v1;
    }
}

// ---------------------------------------------------------------------------
// K3: GAT1 fused + GEMM2 + sd2, grid = 32 b x 4 i-chunks = 128 blocks.
// Stage h1Tg (straight copy, conflict-free), softmax in A-frags, PV MFMA,
// cross-wave LN(256)+ELU -> g1s in LDS, then h2 = g1s@W2t^T with fused
// s2/d2 dots -> h2Tg bf16 transposed.
// ---------------------------------------------------------------------------
__global__ __launch_bounds__(256) void gat1_gemm2_kernel(
    const unsigned short* __restrict__ h1Tg,
    const float* __restrict__ ps_s, const float* __restrict__ ps_d,
    const float* __restrict__ b1, const float* __restrict__ gamma,
    const float* __restrict__ beta,
    const unsigned short* __restrict__ W2t,
    const float* __restrict__ asrc2, const float* __restrict__ adst2,
    unsigned short* __restrict__ h2Tg, float* __restrict__ s2,
    float* __restrict__ d2) {
    int b = blockIdx.x >> 2;
    int c = blockIdx.x & 3;            // i-chunk of 32 rows
    int tid = threadIdx.x;
    int wave = tid >> 6, lane = tid & 63;
    int h = wave >> 1, m = wave & 1;
    int fr = lane & 15;
    int fk = (lane >> 4) * 8;

    __shared__ __align__(16) unsigned short h1T[2][128][136];  // [h][d][j]
    __shared__ float ssh[2][128];
    __shared__ float dsh[2][128];
    __shared__ float lnred[32][2][2];   // [row][h][sum,sumsq]
    __shared__ __align__(16) unsigned short g1s[32][264];      // LN'd rows
    __shared__ float sdr2[32][2][2];
    __shared__ __align__(16) unsigned short t2[64][40];        // [d2][j_local]

    // stage full slab: straight coalesced copy, conflict-free LDS writes
    {
        const us8* src = (const us8*)(h1Tg + (size_t)b * 32768);
#pragma unroll
        for (int it = 0; it < 16; it++) {
            int i8 = tid + it * 256;       // 0..4095
            int row = i8 >> 4;             // 0..255 = h*128+d
            int j8 = i8 & 15;
            *(us8*)(&h1T[row >> 7][row & 127][j8 * 8]) = src[i8];
        }
        int hh = tid >> 7, j = tid & 127;
        size_t o = ((size_t)b * 128 + j) * 2 + hh;
        ssh[hh][j] = ps_s[o] + ps_s[o + 8192];
        dsh[hh][j] = ps_d[o] + ps_d[o + 8192];
    }
    __syncthreads();

    // softmax for rows i = c*32 + m*16 + fr, head h
    bf16x8 afrag[4];
    {
        float dd = dsh[h][c * 32 + m * 16 + fr];
        float ev[4][8];
        float mx = -1e30f;
#pragma unroll
        for (int ks = 0; ks < 4; ks++)
#pragma unroll
            for (int jj = 0; jj < 8; jj++) {
                float e = dd + ssh[h][ks * 32 + fk + jj];
                e = e >= 0.f ? e : 0.2f * e;
                ev[ks][jj] = e;
                mx = fmaxf(mx, e);
            }
        mx = fmaxf(mx, __shfl_xor(mx, 16, 64));
        mx = fmaxf(mx, __shfl_xor(mx, 32, 64));
        float sm = 0.f;
#pragma unroll
        for (int ks = 0; ks < 4; ks++)
#pragma unroll
            for (int jj = 0; jj < 8; jj++) {
                float e = __expf(ev[ks][jj] - mx);
                ev[ks][jj] = e;
                sm += e;
            }
        sm += __shfl_xor(sm, 16, 64);
        sm += __shfl_xor(sm, 32, 64);
        float inv = 1.f / sm;
#pragma unroll
        for (int ks = 0; ks < 4; ks++) {
            bf16x8 a;
#pragma unroll
            for (int jj = 0; jj < 8; jj++)
                a[jj] = (short)f2bf(ev[ks][jj] * inv);
            afrag[ks] = a;
        }
    }

    // PV MFMA: o[16 rows][128 d of head h]
    f32x4 acc[8] = {};
#pragma unroll
    for (int ks = 0; ks < 4; ks++)
#pragma unroll
        for (int ni = 0; ni < 8; ni++) {
            bf16x8 bv = *(const bf16x8*)(&h1T[h][ni * 16 + fr][ks * 32 + fk]);
            acc[ni] = __builtin_amdgcn_mfma_f32_16x16x32_bf16(
                afrag[ks], bv, acc[ni], 0, 0, 0);
        }

    // epilogue: bias, cross-wave LN(256), ELU -> g1s (LDS, bf16)
    int crow = (lane >> 4) * 4;
    int ccol = lane & 15;
    float bv_[8], gv[8], bev[8];
#pragma unroll
    for (int ni = 0; ni < 8; ni++) {
        int d = h * 128 + ni * 16 + ccol;
        bv_[ni] = b1[d]; gv[ni] = gamma[d]; bev[ni] = beta[d];
    }
    float vv[4][8];
#pragma unroll
    for (int r = 0; r < 4; r++) {
        float s = 0.f, q = 0.f;
#pragma unroll
        for (int ni = 0; ni < 8; ni++) {
            float v = acc[ni][r] + bv_[ni];
            vv[r][ni] = v;
            s += v;
            q += v * v;
        }
        s += __shfl_xor(s, 1, 64); s += __shfl_xor(s, 2, 64);
        s += __shfl_xor(s, 4, 64); s += __shfl_xor(s, 8, 64);
        q += __shfl_xor(q, 1, 64); q += __shfl_xor(q, 2, 64);
        q += __shfl_xor(q, 4, 64); q += __shfl_xor(q, 8, 64);
        if ((lane & 15) == 0) {
            lnred[m * 16 + crow + r][h][0] = s;
            lnred[m * 16 + crow + r][h][1] = q;
        }
    }
    __syncthreads();
#pragma unroll
    for (int r = 0; r < 4; r++) {
        int row = m * 16 + crow + r;
        float s = lnred[row][0][0] + lnred[row][1][0];
        float q = lnred[row][0][1] + lnred[row][1][1];
        float mean = s * (1.f / 256.f);
        float var = q * (1.f / 256.f) - mean * mean;
        float rs = rsqrtf(var + 1e-5f);
#pragma unroll
        for (int ni = 0; ni < 8; ni++) {
            float y = (vv[r][ni] - mean) * rs * gv[ni] + bev[ni];
            y = y > 0.f ? y : (__expf(y) - 1.f);
            g1s[row][h * 128 + ni * 16 + ccol] = f2bf(y);
        }
    }
    __syncthreads();

    // phase 2: h2 = g1s(32x256) @ W2t^T (64x256) with fused s2/d2 dots
    int m2 = wave & 1;     // 16-row m-frag
    int nb = wave >> 1;    // 32-col n-half
    f32x4 acc2[2] = {};
#pragma unroll
    for (int kc = 0; kc < 8; kc++) {
        bf16x8 a = *(const bf16x8*)(&g1s[m2 * 16 + fr][kc * 32 + fk]);
#pragma unroll
        for (int ni = 0; ni < 2; ni++) {
            bf16x8 wv = *(const bf16x8*)(W2t + (size_t)(nb * 32 + ni * 16 + fr) * 256 +
                                         kc * 32 + fk);
            acc2[ni] = __builtin_amdgcn_mfma_f32_16x16x32_bf16(a, wv, acc2[ni], 0, 0, 0);
        }
    }
    float as2[2], ad2[2];
#pragma unroll
    for (int ni = 0; ni < 2; ni++) {
        int n = nb * 32 + ni * 16 + ccol;
        as2[ni] = asrc2[n];
        ad2[ni] = adst2[n];
    }
#pragma unroll
    for (int r = 0; r < 4; r++) {
        int rl = m2 * 16 + crow + r;
        float sp = 0.f, dp = 0.f;
#pragma unroll
        for (int ni = 0; ni < 2; ni++) {
            float v = acc2[ni][r];
            t2[nb * 32 + ni * 16 + ccol][rl] = f2bf(v);
            sp += v * as2[ni];
            dp += v * ad2[ni];
        }
        for (int msk = 1; msk < 16; msk <<= 1) {
            sp += __shfl_xor(sp, msk, 64);
            dp += __shfl_xor(dp, msk, 64);
        }
        if ((lane & 15) == 0) {
            sdr2[rl][nb][0] = sp;
            sdr2[rl][nb][1] = dp;
        }
    }
    __syncthreads();
    if (tid < 32) {
        s2[(size_t)b * 128 + c * 32 + tid] = sdr2[tid][0][0] + sdr2[tid][1][0];
        d2[(size_t)b * 128 + c * 32 + tid] = sdr2[tid][0][1] + sdr2[tid][1][1];
    }
    {
        int d = tid >> 2, q = tid & 3;
        us8 v = *(const us8*)(&t2[d][q * 8]);
        *(us8*)(h2Tg + ((size_t)b * 64 + d) * 128 + c * 32 + q * 8) = v;
    }
}

// ---------------------------------------------------------------------------
// K4: GAT2 fused, grid = 32 b x 2 i-chunks = 64 blocks. Staging is a straight
// copy from h2Tg (conflict-free). Wave-local LN(64) + ELU -> x2b bf16.
// ---------------------------------------------------------------------------
__global__ __launch_bounds__(256) void gat2_fused_kernel(
    const unsigned short* __restrict__ h2Tg, const float* __restrict__ s2,
    const float* __restrict__ d2, const float* __restrict__ b2v,
    const float* __restrict__ gamma, const float* __restrict__ beta,
    unsigned short* __restrict__ x2b) {
    int b = blockIdx.x >> 1;
    int c = blockIdx.x & 1;            // i-chunk of 64 rows
    int tid = threadIdx.x;
    int wave = tid >> 6, lane = tid & 63;
    int fr = lane & 15;
    int fk = (lane >> 4) * 8;

    __shared__ __align__(16) unsigned short h2T[64][136];  // [d][j]
    __shared__ float ssh[128];
    __shared__ float dsh[128];

    {
        const us8* src = (const us8*)(h2Tg + (size_t)b * 64 * 128);
#pragma unroll
        for (int it = 0; it < 4; it++) {
            int i8 = tid + it * 256;       // 0..1023
            int row = i8 >> 4;             // 0..63
            int j8 = i8 & 15;
            *(us8*)(&h2T[row][j8 * 8]) = src[i8];
        }
        if (tid < 128) ssh[tid] = s2[(size_t)b * 128 + tid];
        else dsh[tid - 128] = d2[(size_t)b * 128 + (tid - 128)];
    }
    __syncthreads();

    // softmax for rows i = c*64 + wave*16 + fr
    bf16x8 afrag[4];
    {
        float dd = dsh[c * 64 + wave * 16 + fr];
        float ev[4][8];
        float mx = -1e30f;
#pragma unroll
        for (int ks = 0; ks < 4; ks++)
#pragma unroll
            for (int jj = 0; jj < 8; jj++) {
                float e = dd + ssh[ks * 32 + fk + jj];
                e = e >= 0.f ? e : 0.2f * e;
                ev[ks][jj] = e;
                mx = fmaxf(mx, e);
            }
        mx = fmaxf(mx, __shfl_xor(mx, 16, 64));
        mx = fmaxf(mx, __shfl_xor(mx, 32, 64));
        float sm = 0.f;
#pragma unroll
        for (int ks = 0; ks < 4; ks++)
#pragma unroll
            for (int jj = 0; jj < 8; jj++) {
                float e = __expf(ev[ks][jj] - mx);
                ev[ks][jj] = e;
                sm += e;
            }
        sm += __shfl_xor(sm, 16, 64);
        sm += __shfl_xor(sm, 32, 64);
        float inv = 1.f / sm;
#pragma unroll
        for (int ks = 0; ks < 4; ks++) {
            bf16x8 a;
#pragma unroll
            for (int jj = 0; jj < 8; jj++)
                a[jj] = (short)f2bf(ev[ks][jj] * inv);
            afrag[ks] = a;
        }
    }

    f32x4 acc[4] = {};
#pragma unroll
    for (int ks = 0; ks < 4; ks++)
#pragma unroll
        for (int ni = 0; ni < 4; ni++) {
            bf16x8 bv = *(const bf16x8*)(&h2T[ni * 16 + fr][ks * 32 + fk]);
            acc[ni] = __builtin_amdgcn_mfma_f32_16x16x32_bf16(
                afrag[ks], bv, acc[ni], 0, 0, 0);
        }

    int crow = (lane >> 4) * 4;
    int ccol = lane & 15;
    float bv_[4], gv[4], bev[4];
#pragma unroll
    for (int ni = 0; ni < 4; ni++) {
        int d = ni * 16 + ccol;
        bv_[ni] = b2v[d]; gv[ni] = gamma[d]; bev[ni] = beta[d];
    }
#pragma unroll
    for (int r = 0; r < 4; r++) {
        float v[4];
        float s = 0.f;
#pragma unroll
        for (int ni = 0; ni < 4; ni++) {
            v[ni] = acc[ni][r] + bv_[ni];
            s += v[ni];
        }
        s += __shfl_xor(s, 1, 64); s += __shfl_xor(s, 2, 64);
        s += __shfl_xor(s, 4, 64); s += __shfl_xor(s, 8, 64);
        float mean = s * (1.f / 64.f);
        float sq = 0.f;
#pragma unroll
        for (int ni = 0; ni < 4; ni++) {
            float dv = v[ni] - mean;
            sq += dv * dv;
        }
        sq += __shfl_xor(sq, 1, 64); sq += __shfl_xor(sq, 2, 64);
        sq += __shfl_xor(sq, 4, 64); sq += __shfl_xor(sq, 8, 64);
        float rs = rsqrtf(sq * (1.f / 64.f) + 1e-5f);
        int i = c * 64 + wave * 16 + crow + r;
        unsigned short* dst = x2b + (size_t)(b * 128 + i) * 64;
#pragma unroll
        for (int ni = 0; ni < 4; ni++) {
            float y = (v[ni] - mean) * rs * gv[ni] + bev[ni];
            y = y > 0.f ? y : (__expf(y) - 1.f);
            dst[ni * 16 + ccol] = f2bf(y);
        }
    }
}

// ---------------------------------------------------------------------------
// K5: scores via MFMA. 64 pairs per block, N=256, K=160. (unchanged)
// ---------------------------------------------------------------------------
__global__ __launch_bounds__(256) void score_mfma_kernel(
    const unsigned short* __restrict__ x2b, const float* __restrict__ basep,
    const float* __restrict__ br1,
    const int* __restrict__ pair_idx, const int* __restrict__ rel_ids,
    const unsigned short* __restrict__ rembb, const unsigned short* __restrict__ Wtr,
    const float* __restrict__ Wr2, const float* __restrict__ br2,
    float* __restrict__ out) {
    int blk = blockIdx.x;
    int b = blk >> 3;
    int p0 = (blk & 7) * 64;
    int tid = threadIdx.x;
    int wave = tid >> 6, lane = tid & 63;
    int wn = wave * 64;

    __shared__ __align__(16) unsigned short As[64][168];
    __shared__ __align__(16) unsigned short Bs[256][40];
    __shared__ float sred[64][4];
    __shared__ int prs[64][3];

    if (tid < 64) {
        int p = p0 + tid;
        prs[tid][0] = pair_idx[((size_t)b * PP + p) * 2 + 0];
        prs[tid][1] = pair_idx[((size_t)b * PP + p) * 2 + 1];
        prs[tid][2] = rel_ids[(size_t)b * PP + p];
    }
    __syncthreads();
    for (int it = 0; it < 10; it++) {
        int idx = tid + it * 256;
        int m = idx / 40, c = idx % 40;
        int k0 = c * 4;
        us4 v;
        if (k0 < 64)
            v = *(const us4*)(x2b + ((size_t)b * EE + prs[m][0]) * 64 + k0);
        else if (k0 < 128)
            v = *(const us4*)(x2b + ((size_t)b * EE + prs[m][1]) * 64 + (k0 - 64));
        else
            v = *(const us4*)(rembb + prs[m][2] * RDD + (k0 - 128));
        *(us4*)(&As[m][k0]) = v;
    }

    f32x4 acc[4][4] = {};
    int fr = lane & 15;
    int fk = (lane >> 4) * 8;

    for (int kc = 0; kc < 5; kc++) {
        for (int it = 0; it < 4; it++) {
            int i = tid + it * 256;
            int n = i >> 2, c = i & 3;
            *(us8*)(&Bs[n][c * 8]) =
                *(const us8*)(Wtr + (size_t)n * 160 + kc * 32 + c * 8);
        }
        __syncthreads();
        bf16x8 a[4], bv[4];
#pragma unroll
        for (int mi = 0; mi < 4; mi++)
            a[mi] = *(const bf16x8*)(&As[mi * 16 + fr][kc * 32 + fk]);
#pragma unroll
        for (int ni = 0; ni < 4; ni++)
            bv[ni] = *(const bf16x8*)(&Bs[wn + ni * 16 + fr][fk]);
#pragma unroll
        for (int mi = 0; mi < 4; mi++)
#pragma unroll
            for (int ni = 0; ni < 4; ni++)
                acc[mi][ni] = __builtin_amdgcn_mfma_f32_16x16x32_bf16(
                    a[mi], bv[ni], acc[mi][ni], 0, 0, 0);
        __syncthreads();
    }

    int crow = (lane >> 4) * 4;
    int ccol = lane & 15;
    float basev[4], w2v[4];
#pragma unroll
    for (int ni = 0; ni < 4; ni++) {
        int n = wn + ni * 16 + ccol;
        float bb = br1[n];
#pragma unroll
        for (int kc = 0; kc < 12; kc++)
            bb += basep[((size_t)kc * 32 + b) * 256 + n];
        basev[ni] = bb;
        w2v[ni] = Wr2[n];
    }
#pragma unroll
    for (int mi = 0; mi < 4; mi++) {
#pragma unroll
        for (int r = 0; r < 4; r++) {
            float p = 0.f;
#pragma unroll
            for (int ni = 0; ni < 4; ni++)
                p += fmaxf(acc[mi][ni][r] + basev[ni], 0.f) * w2v[ni];
            for (int msk = 1; msk < 16; msk <<= 1)
                p += __shfl_xor(p, msk, 64);
            if ((lane & 15) == 0)
                sred[mi * 16 + crow + r][wave] = p;
        }
    }
    __syncthreads();
    if (tid < 64) {
        float s = sred[tid][0] + sred[tid][1] + sred[tid][2] + sred[tid][3] + br2[0];
        out[(size_t)b * PP + p0 + tid] = s;
    }
}

// ---------------------------------------------------------------------------
extern "C" void kernel_launch(void* const* d_in, const int* in_sizes, int n_in,
                              void* d_out, int out_size, void* d_ws, size_t ws_size,
                              hipStream_t stream) {
    (void)in_sizes; (void)n_in; (void)out_size; (void)ws_size;
    const float* seq      = (const float*)d_in[0];
    const int*   starts   = (const int*)d_in[1];
    const int*   types    = (const int*)d_in[2];
    const int*   pair_idx = (const int*)d_in[3];
    const int*   rel_ids  = (const int*)d_in[4];
    const float* temb     = (const float*)d_in[5];
    const float* remb     = (const float*)d_in[6];
    const float* W1       = (const float*)d_in[7];
    const float* a_src1   = (const float*)d_in[8];
    const float* a_dst1   = (const float*)d_in[9];
    const float* b1       = (const float*)d_in[10];
    const float* ln1_g    = (const float*)d_in[11];
    const float* ln1_b    = (const float*)d_in[12];
    const float* W2       = (const float*)d_in[13];
    const float* a_src2   = (const float*)d_in[14];
    const float* a_dst2   = (const float*)d_in[15];
    const float* b2       = (const float*)d_in[16];
    const float* ln2_g    = (const float*)d_in[17];
    const float* ln2_b    = (const float*)d_in[18];
    const float* Wr1      = (const float*)d_in[19];
    const float* br1      = (const float*)d_in[20];
    const float* Wr2      = (const float*)d_in[21];
    const float* br2      = (const float*)d_in[22];
    float* out = (float*)d_out;

    unsigned short* xb    = (unsigned short*)d_ws;        // 4096*768
    unsigned short* Wt    = xb + (size_t)4096 * 768;      // 256*768
    unsigned short* Wtr   = Wt + (size_t)256 * 768;       // 256*160
    unsigned short* W2t   = Wtr + (size_t)256 * 160;      // 64*256
    unsigned short* rembb = W2t + (size_t)64 * 256;       // 512
    unsigned short* h1Tg  = rembb + 512;                  // 4096*256 (32*2*128*128)
    unsigned short* h2Tg  = h1Tg + (size_t)4096 * 256;    // 32*64*128
    unsigned short* x2b   = h2Tg + (size_t)32 * 64 * 128; // 4096*64
    float* fbase = (float*)(x2b + (size_t)4096 * 64);
    float* ps_s  = fbase;                      // 2*8192
    float* ps_d  = ps_s + 2 * 8192;            // 2*8192
    float* s2    = ps_d + 2 * 8192;            // 4096
    float* d2    = s2 + 4096;                  // 4096
    float* basep = d2 + 4096;                  // 12*32*256

    pool_prep_kernel<<<BB * EE + 75 + 12 * 32, 256, 0, stream>>>(
        seq, starts, types, temb, xb, W1, Wt, Wr1, Wtr, W2, W2t, remb, rembb, basep);
    gemm1_mfma_kernel<<<dim3(4, 64), 256, 0, stream>>>(xb, Wt, a_src1, a_dst1,
                                                       h1Tg, ps_s, ps_d);
    gat1_gemm2_kernel<<<BB * 4, 256, 0, stream>>>(h1Tg, ps_s, ps_d, b1, ln1_g, ln1_b,
                                                  W2t, a_src2, a_dst2, h2Tg, s2, d2);
    gat2_fused_kernel<<<BB * 2, 256, 0, stream>>>(h2Tg, s2, d2, b2, ln2_g, ln2_b, x2b);
    score_mfma_kernel<<<BB * PP / 64, 256, 0, stream>>>(x2b, basep, br1, pair_idx,
                                                        rel_ids, rembb, Wtr, Wr2,
                                                        br2, out);
}